// Round 8
// baseline (30.441 us; speedup 1.0000x reference)
//
#include <hip/hip_runtime.h>
#include <math.h>

#define D_IN 512
#define NQ 4
#define QD 6
#define SPW 16              // samples per wave
#define WPB 4               // waves per block
#define SPB (SPW * WPB)     // 64 samples per block

__device__ __forceinline__ float dot4(float4 a, float4 b) {
    return a.x * b.x + a.y * b.y + a.z * b.z + a.w * b.w;
}

// ---------------------------------------------------------------------------
// Fused kernel, wave-autonomous edition (NO __syncthreads).
// Each wave independently:
//   P1: GEMV+tanh for its 16 samples — round-3's best config: 2 chunks of 8
//       samples, 16 float4 loads in flight per chunk, weights in registers,
//       10-shuffle fold; lanes 0..3 write half-angles to a per-wave LDS slice.
//   P2: lanes 0..15 each sim one of the wave's own samples (fully-unrolled
//       4-qubit statevector + post-net). Same-wave LDS write->read needs only
//       the compiler's lgkmcnt, no barrier.
// Removing the block barrier means waves drift: some wave on the CU is always
// issuing global loads, and the sim tail is hidden under sibling waves' P1.
// ---------------------------------------------------------------------------
__global__ __launch_bounds__(256, 4) void dqn_fused(
    const float* __restrict__ x,
    const float* __restrict__ pre_w,
    const float* __restrict__ pre_b,
    const float* __restrict__ q_params,
    const float* __restrict__ post_w,
    const float* __restrict__ post_b,
    float* __restrict__ out,
    int nsamp)
{
    __shared__ __align__(16) float ang[WPB][SPW][NQ];   // per-wave slices, 1 KB

    const int lane = threadIdx.x & 63;
    const int wv   = threadIdx.x >> 6;
    const int s0   = blockIdx.x * SPB + wv * SPW;

    // ---------------- P1: GEMV (round-3 burst structure) ----------------
    if (s0 < nsamp) {
        const float4* xr = reinterpret_cast<const float4*>(x);
        const float4* wr = reinterpret_cast<const float4*>(pre_w);

        float4 wA[4], wB[4];
#pragma unroll
        for (int q = 0; q < 4; ++q) {
            wA[q] = wr[q * (D_IN / 4) + lane];
            wB[q] = wr[q * (D_IN / 4) + 64 + lane];
        }
        const float bias = pre_b[lane & 3];

#pragma unroll
        for (int ch = 0; ch < SPW / 8; ++ch) {
            // batch-issue 16 float4 loads (8 samples)
            float4 xa[8], xb[8];
#pragma unroll
            for (int j = 0; j < 8; ++j) {
                const size_t row = (size_t)(s0 + ch * 8 + j) * (D_IN / 4);
                xa[j] = xr[row + lane];
                xb[j] = xr[row + 64 + lane];
            }
#pragma unroll
            for (int j = 0; j < 8; ++j) {
                float a0 = dot4(xa[j], wA[0]) + dot4(xb[j], wB[0]);
                float a1 = dot4(xa[j], wA[1]) + dot4(xb[j], wB[1]);
                float a2 = dot4(xa[j], wA[2]) + dot4(xb[j], wB[2]);
                float a3 = dot4(xa[j], wA[3]) + dot4(xb[j], wB[3]);

                // fold 4 accumulators -> lane carries qubit (lane&3)
                a0 += __shfl_xor(a0, 1, 64);
                a1 += __shfl_xor(a1, 1, 64);
                a2 += __shfl_xor(a2, 1, 64);
                a3 += __shfl_xor(a3, 1, 64);
                float b0 = (lane & 1) ? a1 : a0;
                float b1 = (lane & 1) ? a3 : a2;
                b0 += __shfl_xor(b0, 2, 64);
                b1 += __shfl_xor(b1, 2, 64);
                float c = (lane & 2) ? b1 : b0;
                c += __shfl_xor(c, 4, 64);
                c += __shfl_xor(c, 8, 64);
                c += __shfl_xor(c, 16, 64);
                c += __shfl_xor(c, 32, 64);

                float t = c + bias;
                // tanh(t) = 1 - 2/(e^{2t}+1); __expf inf -> tanh -> 1 (ok)
                float e = __expf(2.0f * t);
                float th = 1.0f - 2.0f / (e + 1.0f);
                if (lane < 4)
                    ang[wv][ch * 8 + j][lane] = th * 0.78539816339744831f;
            }
        }
    }
    // no __syncthreads(): same-wave LDS dependency, compiler inserts lgkmcnt

    // ---------------- P2: sim + post-net (lanes 0..15 of each wave) ----------------
    if (lane < SPW) {
        const int b = s0 + lane;
        if (b < nsamp) {
            float4 ha = *reinterpret_cast<const float4*>(&ang[wv][lane][0]);
            float s0_, c0_, s1_, c1_, s2_, c2_, s3_, c3_;
            __sincosf(ha.x, &s0_, &c0_);
            __sincosf(ha.y, &s1_, &c1_);
            __sincosf(ha.z, &s2_, &c2_);
            __sincosf(ha.w, &s3_, &c3_);

            const float r2 = 0.70710678118654752f;
            float A0[2] = {(c0_ - s0_) * r2, (c0_ + s0_) * r2};
            float A1[2] = {(c1_ - s1_) * r2, (c1_ + s1_) * r2};
            float A2[2] = {(c2_ - s2_) * r2, (c2_ + s2_) * r2};
            float A3[2] = {(c3_ - s3_) * r2, (c3_ + s3_) * r2};

            float u[4], v[4], st[16];
#pragma unroll
            for (int i = 0; i < 4; ++i) { u[i] = A0[i >> 1] * A1[i & 1]; v[i] = A2[i >> 1] * A3[i & 1]; }
#pragma unroll
            for (int i = 0; i < 16; ++i) st[i] = u[i >> 2] * v[i & 3];

#pragma unroll
            for (int k = 0; k < QD; ++k) {
                // CNOT(0,1): b0=1 -> swap b1 (compile-time reg permutation)
#pragma unroll
                for (int j = 0; j < 4; ++j) { float tt = st[8 + j]; st[8 + j] = st[12 + j]; st[12 + j] = tt; }
                // CNOT(2,3): b2=1 -> swap b3
#pragma unroll
                for (int j = 0; j < 4; ++j) { float tt = st[4 * j + 2]; st[4 * j + 2] = st[4 * j + 3]; st[4 * j + 3] = tt; }
                // CNOT(1,2): b1=1 -> swap b2
#pragma unroll
                for (int j = 0; j < 2; ++j)
#pragma unroll
                    for (int d = 0; d < 2; ++d) {
                        const int i0 = j * 8 + 4 + d;
                        float tt = st[i0]; st[i0] = st[i0 + 2]; st[i0 + 2] = tt;
                    }
                // RY on each wire (per-layer sincos keeps VGPR low)
                float qc[NQ], qs[NQ];
#pragma unroll
                for (int w = 0; w < NQ; ++w)
                    __sincosf(q_params[k * NQ + w] * 0.5f, &qs[w], &qc[w]);
#pragma unroll
                for (int w = 0; w < NQ; ++w) {
                    const int m = 8 >> w;
                    const float c = qc[w], s = qs[w];
#pragma unroll
                    for (int i = 0; i < 16; ++i) {
                        if ((i & m) == 0) {
                            float x0 = st[i], x1 = st[i | m];
                            st[i]     = c * x0 - s * x1;
                            st[i | m] = s * x0 + c * x1;
                        }
                    }
                }
            }

            float e0 = 0.f, e1 = 0.f, e2 = 0.f, e3 = 0.f;
#pragma unroll
            for (int i = 0; i < 16; ++i) {
                float p = st[i] * st[i];
                e0 += (i & 8) ? -p : p;
                e1 += (i & 4) ? -p : p;
                e2 += (i & 2) ? -p : p;
                e3 += (i & 1) ? -p : p;
            }

            float r[10];
#pragma unroll
            for (int c = 0; c < 10; ++c) {
                r[c] = post_b[c] + e0 * post_w[c * 4 + 0] + e1 * post_w[c * 4 + 1]
                     + e2 * post_w[c * 4 + 2] + e3 * post_w[c * 4 + 3];
            }
            float2* orow = reinterpret_cast<float2*>(out + (size_t)b * 10);
#pragma unroll
            for (int c = 0; c < 5; ++c)
                orow[c] = make_float2(r[2 * c], r[2 * c + 1]);
        }
    }
}

extern "C" void kernel_launch(void* const* d_in, const int* in_sizes, int n_in,
                              void* d_out, int out_size, void* d_ws, size_t ws_size,
                              hipStream_t stream)
{
    const float* x      = (const float*)d_in[0];
    const float* pre_w  = (const float*)d_in[1];
    const float* pre_b  = (const float*)d_in[2];
    const float* q_par  = (const float*)d_in[3];
    const float* post_w = (const float*)d_in[4];
    const float* post_b = (const float*)d_in[5];
    float* out = (float*)d_out;

    const int nsamp = in_sizes[0] / D_IN;              // 65536
    dim3 blk(256);
    dim3 grid((nsamp + SPB - 1) / SPB);                // 1024 blocks
    dqn_fused<<<grid, blk, 0, stream>>>(x, pre_w, pre_b, q_par, post_w, post_b, out, nsamp);
}

// Round 9
// 28.650 us; speedup vs baseline: 1.0625x; 1.0625x over previous
//
#include <hip/hip_runtime.h>
#include <math.h>

#define D_IN 512
#define NQ 4
#define QD 6
#define SPW 16              // samples per wave (GEMV phase)
#define WPB 4               // waves per block
#define SPB (SPW * WPB)     // 64 samples per block

__device__ __forceinline__ float dot4(float4 a, float4 b) {
    return a.x * b.x + a.y * b.y + a.z * b.z + a.w * b.w;
}

// DPP cross-lane add: v += v_from_lane(perm). VALU-only (no DS pipe).
// ctrl: quad_perm -> 0x00-0xFF, row_ror:N -> 0x120+N (rows of 16).
template <int CTRL>
__device__ __forceinline__ float dpp_add(float v) {
    int s = __builtin_amdgcn_mov_dpp(__float_as_int(v), CTRL, 0xF, 0xF, true);
    return v + __int_as_float(s);
}

// ---------------------------------------------------------------------------
// Fused kernel — round-3 structure, DS-diet fold edition.
// Phase 1 (all 4 waves): pre-net GEMV + tanh, 16 samples/wave in 2 chunks of
//   8 (16 float4 loads in flight), weights in registers. Fold now uses DPP
//   (quad_perm xor1/xor2, row_ror 4/8) -> only 2 DS shuffles per sample
//   (xor16, xor32) instead of 10; DS-pipe ops drop 80%.
// Phase 2 (threads 0..63): fully-unrolled 4-qubit statevector sim + post-net,
//   one sample per thread.
// ---------------------------------------------------------------------------
__global__ __launch_bounds__(256, 4) void dqn_fused(
    const float* __restrict__ x,
    const float* __restrict__ pre_w,
    const float* __restrict__ pre_b,
    const float* __restrict__ q_params,
    const float* __restrict__ post_w,
    const float* __restrict__ post_b,
    float* __restrict__ out,
    int nsamp)
{
    __shared__ __align__(16) float ang[SPB][NQ];   // half-angles, 1 KB

    const int lane = threadIdx.x & 63;
    const int wv   = threadIdx.x >> 6;
    const int blk0 = blockIdx.x * SPB;

    // ---------------- phase 1: GEMV ----------------
    {
        const int s0 = blk0 + wv * SPW;
        if (s0 < nsamp) {
            const float4* xr = reinterpret_cast<const float4*>(x);
            const float4* wr = reinterpret_cast<const float4*>(pre_w);

            float4 wA[4], wB[4];
#pragma unroll
            for (int q = 0; q < 4; ++q) {
                wA[q] = wr[q * (D_IN / 4) + lane];
                wB[q] = wr[q * (D_IN / 4) + 64 + lane];
            }
            const float bias = pre_b[lane & 3];

#pragma unroll
            for (int ch = 0; ch < SPW / 8; ++ch) {
                // batch-issue 16 float4 loads (8 samples)
                float4 xa[8], xb[8];
#pragma unroll
                for (int j = 0; j < 8; ++j) {
                    const size_t row = (size_t)(s0 + ch * 8 + j) * (D_IN / 4);
                    xa[j] = xr[row + lane];
                    xb[j] = xr[row + 64 + lane];
                }
#pragma unroll
                for (int j = 0; j < 8; ++j) {
                    float a0 = dot4(xa[j], wA[0]) + dot4(xb[j], wB[0]);
                    float a1 = dot4(xa[j], wA[1]) + dot4(xb[j], wB[1]);
                    float a2 = dot4(xa[j], wA[2]) + dot4(xb[j], wB[2]);
                    float a3 = dot4(xa[j], wA[3]) + dot4(xb[j], wB[3]);

                    // qubit fold within quads (DPP, VALU-only)
                    a0 = dpp_add<0xB1>(a0);        // xor1: quad_perm[1,0,3,2]
                    a1 = dpp_add<0xB1>(a1);
                    a2 = dpp_add<0xB1>(a2);
                    a3 = dpp_add<0xB1>(a3);
                    float b0 = (lane & 1) ? a1 : a0;
                    float b1 = (lane & 1) ? a3 : a2;
                    b0 = dpp_add<0x4E>(b0);        // xor2: quad_perm[2,3,0,1]
                    b1 = dpp_add<0x4E>(b1);
                    float c = (lane & 2) ? b1 : b0;
                    // cross-group sum within each row of 16: ror4 + ror8
                    // closes the mod-4 residue class {l, l+4, l+8, l+12}
                    c = dpp_add<0x124>(c);         // row_ror:4
                    c = dpp_add<0x128>(c);         // row_ror:8
                    // across 16-lane rows (only remaining DS ops)
                    c += __shfl_xor(c, 16, 64);
                    c += __shfl_xor(c, 32, 64);

                    float t = c + bias;
                    // tanh(t) = 1 - 2/(e^{2t}+1); __expf inf -> tanh -> 1 (ok)
                    float e = __expf(2.0f * t);
                    float th = 1.0f - 2.0f / (e + 1.0f);
                    if (lane < 4)
                        ang[wv * SPW + ch * 8 + j][lane] = th * 0.78539816339744831f;
                }
            }
        }
    }
    __syncthreads();

    // ---------------- phase 2: sim + post-net (threads 0..SPB-1) ----------------
    if (threadIdx.x < SPB) {
        const int t = threadIdx.x;
        const int b = blk0 + t;
        if (b < nsamp) {
            float qc[QD][NQ], qs[QD][NQ];
#pragma unroll
            for (int k = 0; k < QD; ++k)
#pragma unroll
                for (int w = 0; w < NQ; ++w)
                    __sincosf(q_params[k * NQ + w] * 0.5f, &qs[k][w], &qc[k][w]);

            float4 ha = *reinterpret_cast<const float4*>(&ang[t][0]);
            float s0_, c0_, s1_, c1_, s2_, c2_, s3_, c3_;
            __sincosf(ha.x, &s0_, &c0_);
            __sincosf(ha.y, &s1_, &c1_);
            __sincosf(ha.z, &s2_, &c2_);
            __sincosf(ha.w, &s3_, &c3_);

            const float r2 = 0.70710678118654752f;
            float A0[2] = {(c0_ - s0_) * r2, (c0_ + s0_) * r2};
            float A1[2] = {(c1_ - s1_) * r2, (c1_ + s1_) * r2};
            float A2[2] = {(c2_ - s2_) * r2, (c2_ + s2_) * r2};
            float A3[2] = {(c3_ - s3_) * r2, (c3_ + s3_) * r2};

            float u[4], v[4], st[16];
#pragma unroll
            for (int i = 0; i < 4; ++i) { u[i] = A0[i >> 1] * A1[i & 1]; v[i] = A2[i >> 1] * A3[i & 1]; }
#pragma unroll
            for (int i = 0; i < 16; ++i) st[i] = u[i >> 2] * v[i & 3];

#pragma unroll
            for (int k = 0; k < QD; ++k) {
                // CNOT(0,1): b0=1 -> swap b1 (compile-time reg permutation)
#pragma unroll
                for (int j = 0; j < 4; ++j) { float tt = st[8 + j]; st[8 + j] = st[12 + j]; st[12 + j] = tt; }
                // CNOT(2,3): b2=1 -> swap b3
#pragma unroll
                for (int j = 0; j < 4; ++j) { float tt = st[4 * j + 2]; st[4 * j + 2] = st[4 * j + 3]; st[4 * j + 3] = tt; }
                // CNOT(1,2): b1=1 -> swap b2
#pragma unroll
                for (int j = 0; j < 2; ++j)
#pragma unroll
                    for (int d = 0; d < 2; ++d) {
                        const int i0 = j * 8 + 4 + d;
                        float tt = st[i0]; st[i0] = st[i0 + 2]; st[i0 + 2] = tt;
                    }
                // RY on each wire
#pragma unroll
                for (int w = 0; w < NQ; ++w) {
                    const int m = 8 >> w;
                    const float c = qc[k][w], s = qs[k][w];
#pragma unroll
                    for (int i = 0; i < 16; ++i) {
                        if ((i & m) == 0) {
                            float x0 = st[i], x1 = st[i | m];
                            st[i]     = c * x0 - s * x1;
                            st[i | m] = s * x0 + c * x1;
                        }
                    }
                }
            }

            float e0 = 0.f, e1 = 0.f, e2 = 0.f, e3 = 0.f;
#pragma unroll
            for (int i = 0; i < 16; ++i) {
                float p = st[i] * st[i];
                e0 += (i & 8) ? -p : p;
                e1 += (i & 4) ? -p : p;
                e2 += (i & 2) ? -p : p;
                e3 += (i & 1) ? -p : p;
            }

            float r[10];
#pragma unroll
            for (int c = 0; c < 10; ++c) {
                r[c] = post_b[c] + e0 * post_w[c * 4 + 0] + e1 * post_w[c * 4 + 1]
                     + e2 * post_w[c * 4 + 2] + e3 * post_w[c * 4 + 3];
            }
            float2* orow = reinterpret_cast<float2*>(out + (size_t)b * 10);
#pragma unroll
            for (int c = 0; c < 5; ++c)
                orow[c] = make_float2(r[2 * c], r[2 * c + 1]);
        }
    }
}

extern "C" void kernel_launch(void* const* d_in, const int* in_sizes, int n_in,
                              void* d_out, int out_size, void* d_ws, size_t ws_size,
                              hipStream_t stream)
{
    const float* x      = (const float*)d_in[0];
    const float* pre_w  = (const float*)d_in[1];
    const float* pre_b  = (const float*)d_in[2];
    const float* q_par  = (const float*)d_in[3];
    const float* post_w = (const float*)d_in[4];
    const float* post_b = (const float*)d_in[5];
    float* out = (float*)d_out;

    const int nsamp = in_sizes[0] / D_IN;              // 65536
    dim3 blk(256);
    dim3 grid((nsamp + SPB - 1) / SPB);                // 1024 blocks
    dqn_fused<<<grid, blk, 0, stream>>>(x, pre_w, pre_b, q_par, post_w, post_b, out, nsamp);
}